// Round 17
// baseline (2620.207 us; speedup 1.0000x reference)
//
#include <hip/hip_runtime.h>
#include <hip/hip_bf16.h>

#define NH 16
#define HD 64
#define SEQ 2048
#define HID 1024
#define MAXP 2048
#define ST_R 76   // u16 stride of transposed R tiles; 152B rows: b64-aligned,
                  // and 6*li mod 32 covers all 16 even banks once -> 2-way reads

typedef float f32x4 __attribute__((ext_vector_type(4)));
typedef short bf16x8 __attribute__((ext_vector_type(8)));
typedef unsigned short u16;
typedef unsigned short u16x8 __attribute__((ext_vector_type(8)));

// Scalar HW convert; compiler fuses adjacent pairs into v_cvt_pk_bf16_f32 (m240).
__device__ __forceinline__ u16 f2bf_hw(float x) {
  union { __hip_bfloat16 h; u16 u; } v;
  v.h = __float2bfloat16(x);
  return v.u;
}
__device__ __forceinline__ unsigned pk2(float a, float b) {
  return (unsigned)f2bf_hw(a) | ((unsigned)f2bf_hw(b) << 16);
}
__device__ __forceinline__ float bf2f(u16 h) {
  union { unsigned u; float f; } v; v.u = ((unsigned)h) << 16;
  return v.f;
}

// XOR-swizzle for bf16 tiles with 64-elem (128B) row stride.
#define SWZ(r, c) ((r) * 64 + ((((c) >> 3) ^ ((r) & 7)) << 3) + ((c) & 7))

// async global->LDS 16B: LDS dest = wave-uniform base + lane*16; global src per-lane.
__device__ __forceinline__ void async_copy16(void* lds, const void* g) {
  __builtin_amdgcn_global_load_lds(
      (const __attribute__((address_space(1))) unsigned int*)g,
      (__attribute__((address_space(3))) unsigned int*)lds, 16, 0, 0);
}
__device__ __forceinline__ void vwait0() { asm volatile("s_waitcnt vmcnt(0)" ::: "memory"); }
__device__ __forceinline__ void vwait2() { asm volatile("s_waitcnt vmcnt(2)" ::: "memory"); }
__device__ __forceinline__ void lwait0() { asm volatile("s_waitcnt lgkmcnt(0)" ::: "memory"); }

// ---------------- fused fp32 -> bf16 bulk convert (5 regions, 1 launch) ----------------
__global__ __launch_bounds__(256) void cvt_multi(
    const float* __restrict__ s0, const float* __restrict__ s1,
    const float* __restrict__ s2, const float* __restrict__ s3,
    const float* __restrict__ s4,
    u16* __restrict__ d0, u16* __restrict__ d1, u16* __restrict__ d2,
    u16* __restrict__ d3, u16* __restrict__ d4) {
  const float* s; u16* d; int n4;
  switch (blockIdx.y) {
    case 0: s = s0; d = d0; n4 = 1048576; break;   // hidden_states
    case 1: s = s1; d = d1; n4 = 262144; break;    // Wq
    case 2: s = s2; d = d2; n4 = 262144; break;    // Wk
    case 3: s = s3; d = d3; n4 = 262144; break;    // Wv
    default: s = s4; d = d4; n4 = 65520; break;    // dist_emb
  }
  int i = blockIdx.x * 256 + threadIdx.x;
  const int stride = gridDim.x * 256;
  for (; i < n4; i += stride) {
    const float4 v = reinterpret_cast<const float4*>(s)[i];
    uint2 o;
    o.x = pk2(v.x, v.y);
    o.y = pk2(v.z, v.w);
    reinterpret_cast<uint2*>(d)[i] = o;
  }
}

// ---------------- Fused Q/K/V projection: O = bf16((X @ W^T + b) * scale) ----
// Q (wsel==0) pre-scaled by 0.125 (exact in bf16) to fold 1/sqrt(64).
__global__ __launch_bounds__(256) void proj_mfma(
    const u16* __restrict__ Xb, const u16* __restrict__ W0,
    const u16* __restrict__ W1, const u16* __restrict__ W2,
    const float* __restrict__ b0, const float* __restrict__ b1,
    const float* __restrict__ b2,
    u16* __restrict__ O0, u16* __restrict__ O1, u16* __restrict__ O2) {
  __shared__ u16 sA[128 * 64];
  __shared__ u16 sB[128 * 64];
  const int t = threadIdx.x, lane = t & 63, w = t >> 6;
  const int g = lane >> 4, li = lane & 15;
  const int wsel = blockIdx.x >> 3;
  const int n0 = (blockIdx.x & 7) * 128, m0 = blockIdx.y * 128;
  const u16* Wb = wsel == 0 ? W0 : (wsel == 1 ? W1 : W2);
  const float* bias = wsel == 0 ? b0 : (wsel == 1 ? b1 : b2);
  u16* Ob = wsel == 0 ? O0 : (wsel == 1 ? O1 : O2);
  const float oscale = wsel == 0 ? 0.125f : 1.0f;
  const int wr = w >> 1, wc = w & 1;

  f32x4 acc[4][4];
#pragma unroll
  for (int i = 0; i < 4; ++i)
#pragma unroll
    for (int j = 0; j < 4; ++j) acc[i][j] = (f32x4)0.0f;

  for (int k0 = 0; k0 < HID; k0 += 64) {
    __syncthreads();
#pragma unroll
    for (int i = 0; i < 4; ++i) {
      const int idx = (w * 4 + i) * 64 + lane;
      const int row = idx >> 3, sch = (idx & 7) ^ (row & 7);
      async_copy16(&sA[(w * 4 + i) * 512], Xb + (size_t)(m0 + row) * HID + k0 + sch * 8);
      async_copy16(&sB[(w * 4 + i) * 512], Wb + (size_t)(n0 + row) * HID + k0 + sch * 8);
    }
    __syncthreads();
    bf16x8 af[4][2], bfr[4][2];
#pragma unroll
    for (int i = 0; i < 4; ++i)
#pragma unroll
      for (int c = 0; c < 2; ++c)
        af[i][c] = *reinterpret_cast<const bf16x8*>(&sA[SWZ(wr * 64 + 16 * i + li, 32 * c + 8 * g)]);
#pragma unroll
    for (int j = 0; j < 4; ++j)
#pragma unroll
      for (int c = 0; c < 2; ++c)
        bfr[j][c] = *reinterpret_cast<const bf16x8*>(&sB[SWZ(wc * 64 + 16 * j + li, 32 * c + 8 * g)]);
#pragma unroll
    for (int i = 0; i < 4; ++i)
#pragma unroll
      for (int j = 0; j < 4; ++j)
#pragma unroll
        for (int c = 0; c < 2; ++c)
          acc[i][j] = __builtin_amdgcn_mfma_f32_16x16x32_bf16(af[i][c], bfr[j][c], acc[i][j], 0, 0, 0);
  }

#pragma unroll
  for (int j = 0; j < 4; ++j) {
    const float bj = bias[n0 + wc * 64 + 16 * j + li];
#pragma unroll
    for (int i = 0; i < 4; ++i)
#pragma unroll
      for (int r = 0; r < 4; ++r)
        Ob[(size_t)(m0 + wr * 64 + 16 * i + 4 * g + r) * HID + n0 + wc * 64 + 16 * j + li] =
            f2bf_hw((acc[i][j][r] + bj) * oscale);
  }
}

// ---------------- V transpose: Vt[b][h][d][s] <- V[b][s][h*64+d] ----------------
__global__ __launch_bounds__(256) void transpose_v(
    const u16* __restrict__ Vin, u16* __restrict__ Vt) {
  __shared__ u16 tile[64 * 65];
  const int t = threadIdx.x;
  const int s0 = blockIdx.x * 64, h = blockIdx.y, b = blockIdx.z;
  const int r = t >> 2, c0 = (t & 3) * 16;
  const u16* gp = Vin + (size_t)(b * SEQ + s0 + r) * HID + h * HD + c0;
  const u16x8 a0 = *reinterpret_cast<const u16x8*>(gp);
  const u16x8 a1 = *reinterpret_cast<const u16x8*>(gp + 8);
#pragma unroll
  for (int i = 0; i < 8; ++i) { tile[r * 65 + c0 + i] = a0[i]; tile[r * 65 + c0 + 8 + i] = a1[i]; }
  __syncthreads();
  const int d = t >> 2, sc = (t & 3) * 16;
  u16x8 o0, o1;
#pragma unroll
  for (int i = 0; i < 8; ++i) {
    o0[i] = tile[(sc + i) * 65 + d];
    o1[i] = tile[(sc + 8 + i) * 65 + d];
  }
  u16* op = Vt + ((size_t)(b * NH + h) * HD + d) * SEQ + s0 + sc;
  *reinterpret_cast<u16x8*>(op) = o0;
  *reinterpret_cast<u16x8*>(op + 8) = o1;
}

// ---------------- Fused MFMA attention v12: LDS diet ----------------
// R15 + two LDS-read dedupes (identical addresses & math, fewer ops):
// (1) kA == kB[w]: read the 4 kB fragments once; reuse kB[w] as the R-phase
//     A operand (-2 b128/wave/iter).
// (2) eq/ek union: loop m=0..7 with wave-uniform band predicates
//     (Rq: w..w+4, Rk: 3-w..7-w), read each needed E group ONCE and feed both
//     MFMAs (-4..-8 b128/wave/iter). LDS pipe is the measured bottleneck
//     (~95% busy by op-count model), so removed ops convert ~1:1 to time.
__global__ __launch_bounds__(256, 2) void attn_mfma12(
    const u16* __restrict__ Q, const u16* __restrict__ K,
    const u16* __restrict__ Vt, const u16* __restrict__ E,
    float* __restrict__ out) {
  __shared__ u16 sK0[64 * 64];     // K buffers; current one becomes P after #2
  __shared__ u16 sK1[64 * 64];
  __shared__ u16 sV[64 * 64];
  __shared__ u16 sE[128 * 64];
  __shared__ u16 sRq[128 * ST_R];  // [j][qi] transposed
  __shared__ u16 sRk[128 * ST_R];  // [j][ki]

  const int t = threadIdx.x;
  const int lane = t & 63, w = t >> 6;
  const int g = lane >> 4, li = lane & 15;
  const int q0 = blockIdx.x * 64;
  const int h = blockIdx.y, b = blockIdx.z;
  const size_t qkbase = (size_t)b * SEQ * HID + (size_t)h * HD;
  const size_t vtbase = (size_t)(b * NH + h) * HD * SEQ;

  bf16x8 qA[2];
#pragma unroll
  for (int c = 0; c < 2; ++c)
    qA[c] = *reinterpret_cast<const bf16x8*>(
        Q + qkbase + (size_t)(q0 + 16 * w + li) * HID + 32 * c + 8 * g);

  bf16x8 ones;
#pragma unroll
  for (int i = 0; i < 8; ++i) ones[i] = (short)0x3F80;  // bf16 1.0

  f32x4 accO[4];
  f32x4 accX = (f32x4)0.0f;   // row-sum of P (denominator) via ones-MFMA
#pragma unroll
  for (int n = 0; n < 4; ++n) accO[n] = (f32x4)0.0f;

  // k0-invariant gather bases; j = 63+qi-ki, biased so unrolled offsets
  // are non-negative compile-time constants.
  const int jb48 = 15 + 16 * w + 4 * g - li;             // in [0, 75]
  const u16* gqp = &sRq[jb48 * ST_R + 16 * w + 4 * g];   // + (48+r-16n)*ST_R + r
  const u16* gkp = &sRk[jb48 * ST_R + li];               // + (48+r-16n)*ST_R + 16n
  // R write/E read bases, uniform in m: row (16m+li), column 16w+4g.
  u16* rqw = &sRq[(size_t)li * ST_R + 16 * w + 4 * g];   // + m*16*ST_R
  u16* rkw = &sRk[(size_t)li * ST_R + 16 * w + 4 * g];   // + m*16*ST_R
  const u16* ebase[2];
#pragma unroll
  for (int c = 0; c < 2; ++c)
    ebase[c] = &sE[SWZ(li, 32 * c + 8 * g)];             // + m*1024 (16m*64 u16)

  const int sidx2 = w * 2 * 64 + lane;
  const int sidx4 = w * 4 * 64 + lane;

  // ---- prologue: stage K(0), E(0); drain ----
  {
    const int eb0 = 1984 + q0;
#pragma unroll
    for (int i = 0; i < 2; ++i) {
      const int idx = sidx2 + i * 64;
      const int row = idx >> 3, sch = (idx & 7) ^ (row & 7);
      async_copy16(&sK0[(w * 2 + i) * 512], K + qkbase + (size_t)row * HID + sch * 8);
    }
#pragma unroll
    for (int i = 0; i < 4; ++i) {
      const int idx = sidx4 + i * 64;
      const int row = idx >> 3, sch = (idx & 7) ^ (row & 7);
      const int er = min(max(eb0 + row, 0), 2 * MAXP - 2);
      async_copy16(&sE[(w * 4 + i) * 512], E + (size_t)er * HD + sch * 8);
    }
    vwait0();
  }

  for (int k0 = 0; k0 < SEQ; k0 += 64) {
    const int p = (k0 >> 6) & 1;
    u16* kcur = p ? sK1 : sK0;
    u16* knxt = p ? sK0 : sK1;

    __builtin_amdgcn_s_barrier();   // #1: K(t),E(t) visible; knxt/sV reusable
    // ---- issue V(t) first (oldest), then K(t+1) ----
#pragma unroll
    for (int i = 0; i < 2; ++i) {
      const int idx = sidx2 + i * 64;
      const int row = idx >> 3, sch = (idx & 7) ^ (row & 7);
      async_copy16(&sV[(w * 2 + i) * 512], Vt + vtbase + (size_t)row * SEQ + k0 + sch * 8);
    }
#pragma unroll
    for (int i = 0; i < 2; ++i) {
      const int idx = sidx2 + i * 64;
      const int row = idx >> 3, sch = (idx & 7) ^ (row & 7);
      async_copy16(&knxt[(w * 2 + i) * 512], K + qkbase + (size_t)(k0 + 64 + row) * HID + sch * 8);
    }

    // ---- S = Q'.K^T  (kB[w] doubles as the R-phase A operand) ----
    bf16x8 kB[4][2];
#pragma unroll
    for (int n = 0; n < 4; ++n)
#pragma unroll
      for (int c = 0; c < 2; ++c)
        kB[n][c] = *reinterpret_cast<const bf16x8*>(&kcur[SWZ(16 * n + li, 32 * c + 8 * g)]);
    f32x4 aqk[4];
#pragma unroll
    for (int n = 0; n < 4; ++n) {
      aqk[n] = (f32x4)0.0f;
#pragma unroll
      for (int c = 0; c < 2; ++c)
        aqk[n] = __builtin_amdgcn_mfma_f32_16x16x32_bf16(qA[c], kB[n][c], aqk[n], 0, 0, 0);
    }

    // ---- band-restricted R with E-group union dedupe ----
    __builtin_amdgcn_s_setprio(1);
#pragma unroll
    for (int m = 0; m < 8; ++m) {
      const bool needq = (m >= w) && (m <= w + 4);       // Rq band
      const bool needk = (m >= 3 - w) && (m <= 7 - w);   // Rk band
      if (needq || needk) {
        bf16x8 e0 = *reinterpret_cast<const bf16x8*>(ebase[0] + m * 1024);
        bf16x8 e1 = *reinterpret_cast<const bf16x8*>(ebase[1] + m * 1024);
        if (needq) {
          f32x4 aq = (f32x4)0.0f;
          aq = __builtin_amdgcn_mfma_f32_16x16x32_bf16(qA[0], e0, aq, 0, 0, 0);
          aq = __builtin_amdgcn_mfma_f32_16x16x32_bf16(qA[1], e1, aq, 0, 0, 0);
          uint2 dq;
          dq.x = pk2(aq[0], aq[1]); dq.y = pk2(aq[2], aq[3]);
          *reinterpret_cast<uint2*>(rqw + m * 16 * ST_R) = dq;
        }
        if (needk) {
          f32x4 ak = (f32x4)0.0f;
          ak = __builtin_amdgcn_mfma_f32_16x16x32_bf16(kB[w][0], e0, ak, 0, 0, 0);
          ak = __builtin_amdgcn_mfma_f32_16x16x32_bf16(kB[w][1], e1, ak, 0, 0, 0);
          uint2 dk;
          dk.x = pk2(ak[0], ak[1]); dk.y = pk2(ak[2], ak[3]);
          *reinterpret_cast<uint2*>(rkw + m * 16 * ST_R) = dk;
        }
      }
    }
    __builtin_amdgcn_s_setprio(0);

    vwait2();                       // V(t) landed (oldest 2); K(t+1) stays in flight
    lwait0();                       // R-writes retired
    __builtin_amdgcn_s_barrier();   // #2: sRk/sRq + sV visible to all

    // ---- issue E(t+1) (all sE reads happened before #2) ----
    {
      const int ebn = 1920 + q0 - k0;  // eb(t+1)
#pragma unroll
      for (int i = 0; i < 4; ++i) {
        const int idx = sidx4 + i * 64;
        const int row = idx >> 3, sch = (idx & 7) ^ (row & 7);
        const int er = min(max(ebn + row, 0), 2 * MAXP - 2);
        async_copy16(&sE[(w * 4 + i) * 512], E + (size_t)er * HD + sch * 8);
      }
    }

    // ---- scores: gather + __expf + P write (into kcur, dead K tile) ----
#pragma unroll
    for (int n = 0; n < 4; ++n)
#pragma unroll
      for (int r = 0; r < 4; ++r) {
        const float relq = bf2f(gqp[(48 + r - 16 * n) * ST_R + r]);
        const float relk = bf2f(gkp[(48 + r - 16 * n) * ST_R + 16 * n]);
        const float pr = __expf(fmaf(relk, 0.125f, aqk[n][r] + relq));
        kcur[SWZ(16 * w + 4 * g + r, 16 * n + li)] = f2bf_hw(pr);
      }

    // ---- O += P.V ; accX += P.1 (row-sum on matrix pipe) ----
    bf16x8 pA[2];
#pragma unroll
    for (int c = 0; c < 2; ++c)
      pA[c] = *reinterpret_cast<const bf16x8*>(&kcur[SWZ(16 * w + li, 32 * c + 8 * g)]);
#pragma unroll
    for (int n = 0; n < 4; ++n)
#pragma unroll
      for (int c = 0; c < 2; ++c) {
        const bf16x8 vB = *reinterpret_cast<const bf16x8*>(&sV[SWZ(16 * n + li, 32 * c + 8 * g)]);
        accO[n] = __builtin_amdgcn_mfma_f32_16x16x32_bf16(pA[c], vB, accO[n], 0, 0, 0);
      }
#pragma unroll
    for (int c = 0; c < 2; ++c)
      accX = __builtin_amdgcn_mfma_f32_16x16x32_bf16(pA[c], ones, accX, 0, 0, 0);

    vwait0();                       // K(t+1) + E(t+1) landed
  }

  // ---- epilogue: normalize (accX holds row-sums in every lane), store ----
#pragma unroll
  for (int r = 0; r < 4; ++r) {
    const float inv = 1.0f / accX[r];
    const size_t row = (size_t)(b * SEQ + q0 + 16 * w + 4 * g + r) * HID + h * HD;
#pragma unroll
    for (int n = 0; n < 4; ++n) out[row + 16 * n + li] = accO[n][r] * inv;
  }
}

extern "C" void kernel_launch(void* const* d_in, const int* in_sizes, int n_in,
                              void* d_out, int out_size, void* d_ws, size_t ws_size,
                              hipStream_t stream) {
  const float* hs = (const float*)d_in[0];
  const float* Wq = (const float*)d_in[1];
  const float* bq = (const float*)d_in[2];
  const float* Wk = (const float*)d_in[3];
  const float* bk = (const float*)d_in[4];
  const float* Wv = (const float*)d_in[5];
  const float* bv = (const float*)d_in[6];
  const float* de = (const float*)d_in[7];
  float* out = (float*)d_out;

  // Sizes: hs = 4,194,304 floats; W* = 1,048,576; de = 262,080.
  u16* Xb  = (u16*)d_ws;                 // 4,194,304 u16
  u16* Wqb = Xb + (size_t)4194304;       // 1,048,576 each
  u16* Wkb = Wqb + (size_t)1048576;
  u16* Wvb = Wkb + (size_t)1048576;
  u16* Qb  = Wvb + (size_t)1048576;      // 4,194,304 each
  u16* Kb  = Qb + (size_t)4194304;
  u16* Vb  = Kb + (size_t)4194304;
  u16* Eb  = Vb + (size_t)4194304;       // 262,080
  u16* Vtb = Xb;                         // alias: Xb dead after proj_mfma

  dim3 blk(256);
  hipLaunchKernelGGL(cvt_multi, dim3(1024, 5), blk, 0, stream,
                     hs, Wq, Wk, Wv, de, Xb, Wqb, Wkb, Wvb, Eb);
  hipLaunchKernelGGL(proj_mfma, dim3(24, 32), blk, 0, stream,
                     Xb, Wqb, Wkb, Wvb, bq, bk, bv, Qb, Kb, Vb);
  hipLaunchKernelGGL(transpose_v, dim3(SEQ / 64, NH, 2), blk, 0, stream, Vb, Vtb);
  hipLaunchKernelGGL(attn_mfma12, dim3(SEQ / 64, NH, 2), blk, 0, stream, Qb, Kb, Vtb, Eb, out);
}

// Round 18
// 228.023 us; speedup vs baseline: 11.4910x; 11.4910x over previous
//
#include <hip/hip_runtime.h>
#include <hip/hip_bf16.h>

#define NH 16
#define HD 64
#define SEQ 2048
#define HID 1024
#define MAXP 2048
#define ST_R 76   // u16 stride of transposed R tiles; 152B rows: b64-aligned,
                  // and 6*li mod 32 covers all 16 even banks once -> 2-way reads

typedef float f32x4 __attribute__((ext_vector_type(4)));
typedef short bf16x8 __attribute__((ext_vector_type(8)));
typedef unsigned short u16;
typedef unsigned short u16x8 __attribute__((ext_vector_type(8)));

// Scalar HW convert; compiler fuses adjacent pairs into v_cvt_pk_bf16_f32 (m240).
__device__ __forceinline__ u16 f2bf_hw(float x) {
  union { __hip_bfloat16 h; u16 u; } v;
  v.h = __float2bfloat16(x);
  return v.u;
}
__device__ __forceinline__ unsigned pk2(float a, float b) {
  return (unsigned)f2bf_hw(a) | ((unsigned)f2bf_hw(b) << 16);
}
__device__ __forceinline__ float bf2f(u16 h) {
  union { unsigned u; float f; } v; v.u = ((unsigned)h) << 16;
  return v.f;
}

// XOR-swizzle for bf16 tiles with 64-elem (128B) row stride.
#define SWZ(r, c) ((r) * 64 + ((((c) >> 3) ^ ((r) & 7)) << 3) + ((c) & 7))

// async global->LDS 16B: LDS dest = wave-uniform base + lane*16; global src per-lane.
__device__ __forceinline__ void async_copy16(void* lds, const void* g) {
  __builtin_amdgcn_global_load_lds(
      (const __attribute__((address_space(1))) unsigned int*)g,
      (__attribute__((address_space(3))) unsigned int*)lds, 16, 0, 0);
}
__device__ __forceinline__ void vwait0() { asm volatile("s_waitcnt vmcnt(0)" ::: "memory"); }
__device__ __forceinline__ void vwait2() { asm volatile("s_waitcnt vmcnt(2)" ::: "memory"); }
__device__ __forceinline__ void lwait0() { asm volatile("s_waitcnt lgkmcnt(0)" ::: "memory"); }

// ---------------- fused fp32 -> bf16 bulk convert (5 regions, 1 launch) ----------------
__global__ __launch_bounds__(256) void cvt_multi(
    const float* __restrict__ s0, const float* __restrict__ s1,
    const float* __restrict__ s2, const float* __restrict__ s3,
    const float* __restrict__ s4,
    u16* __restrict__ d0, u16* __restrict__ d1, u16* __restrict__ d2,
    u16* __restrict__ d3, u16* __restrict__ d4) {
  const float* s; u16* d; int n4;
  switch (blockIdx.y) {
    case 0: s = s0; d = d0; n4 = 1048576; break;   // hidden_states
    case 1: s = s1; d = d1; n4 = 262144; break;    // Wq
    case 2: s = s2; d = d2; n4 = 262144; break;    // Wk
    case 3: s = s3; d = d3; n4 = 262144; break;    // Wv
    default: s = s4; d = d4; n4 = 65520; break;    // dist_emb
  }
  int i = blockIdx.x * 256 + threadIdx.x;
  const int stride = gridDim.x * 256;
  for (; i < n4; i += stride) {
    const float4 v = reinterpret_cast<const float4*>(s)[i];
    uint2 o;
    o.x = pk2(v.x, v.y);
    o.y = pk2(v.z, v.w);
    reinterpret_cast<uint2*>(d)[i] = o;
  }
}

// ---------------- Fused Q/K/V projection: O = bf16((X @ W^T + b) * scale) ----
// Q (wsel==0) pre-scaled by 0.125 (exact in bf16) to fold 1/sqrt(64).
__global__ __launch_bounds__(256) void proj_mfma(
    const u16* __restrict__ Xb, const u16* __restrict__ W0,
    const u16* __restrict__ W1, const u16* __restrict__ W2,
    const float* __restrict__ b0, const float* __restrict__ b1,
    const float* __restrict__ b2,
    u16* __restrict__ O0, u16* __restrict__ O1, u16* __restrict__ O2) {
  __shared__ u16 sA[128 * 64];
  __shared__ u16 sB[128 * 64];
  const int t = threadIdx.x, lane = t & 63, w = t >> 6;
  const int g = lane >> 4, li = lane & 15;
  const int wsel = blockIdx.x >> 3;
  const int n0 = (blockIdx.x & 7) * 128, m0 = blockIdx.y * 128;
  const u16* Wb = wsel == 0 ? W0 : (wsel == 1 ? W1 : W2);
  const float* bias = wsel == 0 ? b0 : (wsel == 1 ? b1 : b2);
  u16* Ob = wsel == 0 ? O0 : (wsel == 1 ? O1 : O2);
  const float oscale = wsel == 0 ? 0.125f : 1.0f;
  const int wr = w >> 1, wc = w & 1;

  f32x4 acc[4][4];
#pragma unroll
  for (int i = 0; i < 4; ++i)
#pragma unroll
    for (int j = 0; j < 4; ++j) acc[i][j] = (f32x4)0.0f;

  for (int k0 = 0; k0 < HID; k0 += 64) {
    __syncthreads();
#pragma unroll
    for (int i = 0; i < 4; ++i) {
      const int idx = (w * 4 + i) * 64 + lane;
      const int row = idx >> 3, sch = (idx & 7) ^ (row & 7);
      async_copy16(&sA[(w * 4 + i) * 512], Xb + (size_t)(m0 + row) * HID + k0 + sch * 8);
      async_copy16(&sB[(w * 4 + i) * 512], Wb + (size_t)(n0 + row) * HID + k0 + sch * 8);
    }
    __syncthreads();
    bf16x8 af[4][2], bfr[4][2];
#pragma unroll
    for (int i = 0; i < 4; ++i)
#pragma unroll
      for (int c = 0; c < 2; ++c)
        af[i][c] = *reinterpret_cast<const bf16x8*>(&sA[SWZ(wr * 64 + 16 * i + li, 32 * c + 8 * g)]);
#pragma unroll
    for (int j = 0; j < 4; ++j)
#pragma unroll
      for (int c = 0; c < 2; ++c)
        bfr[j][c] = *reinterpret_cast<const bf16x8*>(&sB[SWZ(wc * 64 + 16 * j + li, 32 * c + 8 * g)]);
#pragma unroll
    for (int i = 0; i < 4; ++i)
#pragma unroll
      for (int j = 0; j < 4; ++j)
#pragma unroll
        for (int c = 0; c < 2; ++c)
          acc[i][j] = __builtin_amdgcn_mfma_f32_16x16x32_bf16(af[i][c], bfr[j][c], acc[i][j], 0, 0, 0);
  }

#pragma unroll
  for (int j = 0; j < 4; ++j) {
    const float bj = bias[n0 + wc * 64 + 16 * j + li];
#pragma unroll
    for (int i = 0; i < 4; ++i)
#pragma unroll
      for (int r = 0; r < 4; ++r)
        Ob[(size_t)(m0 + wr * 64 + 16 * i + 4 * g + r) * HID + n0 + wc * 64 + 16 * j + li] =
            f2bf_hw((acc[i][j][r] + bj) * oscale);
  }
}

// ---------------- V transpose: Vt[b][h][d][s] <- V[b][s][h*64+d] ----------------
__global__ __launch_bounds__(256) void transpose_v(
    const u16* __restrict__ Vin, u16* __restrict__ Vt) {
  __shared__ u16 tile[64 * 65];
  const int t = threadIdx.x;
  const int s0 = blockIdx.x * 64, h = blockIdx.y, b = blockIdx.z;
  const int r = t >> 2, c0 = (t & 3) * 16;
  const u16* gp = Vin + (size_t)(b * SEQ + s0 + r) * HID + h * HD + c0;
  const u16x8 a0 = *reinterpret_cast<const u16x8*>(gp);
  const u16x8 a1 = *reinterpret_cast<const u16x8*>(gp + 8);
#pragma unroll
  for (int i = 0; i < 8; ++i) { tile[r * 65 + c0 + i] = a0[i]; tile[r * 65 + c0 + 8 + i] = a1[i]; }
  __syncthreads();
  const int d = t >> 2, sc = (t & 3) * 16;
  u16x8 o0, o1;
#pragma unroll
  for (int i = 0; i < 8; ++i) {
    o0[i] = tile[(sc + i) * 65 + d];
    o1[i] = tile[(sc + 8 + i) * 65 + d];
  }
  u16* op = Vt + ((size_t)(b * NH + h) * HD + d) * SEQ + s0 + sc;
  *reinterpret_cast<u16x8*>(op) = o0;
  *reinterpret_cast<u16x8*>(op + 8) = o1;
}

// ---- band-restricted R phase, W = wave id as a TEMPLATE constant ----
// All register indices and band predicates fold at compile time (rule #20:
// runtime-indexed register arrays go to scratch — R17's 15x regression).
// Rq needs E-groups W..W+4; Rk needs 3-W..7-W; overlapping groups read ONCE.
template <int W>
__device__ __forceinline__ void r_phase(
    const bf16x8 (&qA)[2], const bf16x8 (&kW)[2],
    const u16* e0base, const u16* e1base, u16* rqw, u16* rkw) {
#pragma unroll
  for (int m = 0; m < 8; ++m) {
    const bool needq = (m >= W) && (m <= W + 4);
    const bool needk = (m >= 3 - W) && (m <= 7 - W);
    if (needq || needk) {
      const bf16x8 e0 = *reinterpret_cast<const bf16x8*>(e0base + m * 1024);
      const bf16x8 e1 = *reinterpret_cast<const bf16x8*>(e1base + m * 1024);
      if (needq) {
        f32x4 aq = (f32x4)0.0f;
        aq = __builtin_amdgcn_mfma_f32_16x16x32_bf16(qA[0], e0, aq, 0, 0, 0);
        aq = __builtin_amdgcn_mfma_f32_16x16x32_bf16(qA[1], e1, aq, 0, 0, 0);
        uint2 dq;
        dq.x = pk2(aq[0], aq[1]); dq.y = pk2(aq[2], aq[3]);
        *reinterpret_cast<uint2*>(rqw + m * 16 * ST_R) = dq;
      }
      if (needk) {
        f32x4 ak = (f32x4)0.0f;
        ak = __builtin_amdgcn_mfma_f32_16x16x32_bf16(kW[0], e0, ak, 0, 0, 0);
        ak = __builtin_amdgcn_mfma_f32_16x16x32_bf16(kW[1], e1, ak, 0, 0, 0);
        uint2 dk;
        dk.x = pk2(ak[0], ak[1]); dk.y = pk2(ak[2], ak[3]);
        *reinterpret_cast<uint2*>(rkw + m * 16 * ST_R) = dk;
      }
    }
  }
}

// ---------------- Fused MFMA attention v13: codegen-safe LDS diet ----------------
// R15 skeleton + (1) kA == kB[w] dedupe and (2) E-group union dedupe, both
// expressed with compile-time register indices via template<W> + wave-uniform
// 4-way branch. Same math/addresses as R14/R15; 8 fewer b128 LDS reads
// per wave/iter on the ~95%-busy LDS pipe.
__global__ __launch_bounds__(256, 2) void attn_mfma13(
    const u16* __restrict__ Q, const u16* __restrict__ K,
    const u16* __restrict__ Vt, const u16* __restrict__ E,
    float* __restrict__ out) {
  __shared__ u16 sK0[64 * 64];     // K buffers; current one becomes P after #2
  __shared__ u16 sK1[64 * 64];
  __shared__ u16 sV[64 * 64];
  __shared__ u16 sE[128 * 64];
  __shared__ u16 sRq[128 * ST_R];  // [j][qi] transposed
  __shared__ u16 sRk[128 * ST_R];  // [j][ki]

  const int t = threadIdx.x;
  const int lane = t & 63, w = t >> 6;
  const int g = lane >> 4, li = lane & 15;
  const int q0 = blockIdx.x * 64;
  const int h = blockIdx.y, b = blockIdx.z;
  const size_t qkbase = (size_t)b * SEQ * HID + (size_t)h * HD;
  const size_t vtbase = (size_t)(b * NH + h) * HD * SEQ;

  bf16x8 qA[2];
#pragma unroll
  for (int c = 0; c < 2; ++c)
    qA[c] = *reinterpret_cast<const bf16x8*>(
        Q + qkbase + (size_t)(q0 + 16 * w + li) * HID + 32 * c + 8 * g);

  bf16x8 ones;
#pragma unroll
  for (int i = 0; i < 8; ++i) ones[i] = (short)0x3F80;  // bf16 1.0

  f32x4 accO[4];
  f32x4 accX = (f32x4)0.0f;   // row-sum of P (denominator) via ones-MFMA
#pragma unroll
  for (int n = 0; n < 4; ++n) accO[n] = (f32x4)0.0f;

  // k0-invariant gather bases; j = 63+qi-ki, biased so unrolled offsets
  // are non-negative compile-time constants.
  const int jb48 = 15 + 16 * w + 4 * g - li;             // in [0, 75]
  const u16* gqp = &sRq[jb48 * ST_R + 16 * w + 4 * g];   // + (48+r-16n)*ST_R + r
  const u16* gkp = &sRk[jb48 * ST_R + li];               // + (48+r-16n)*ST_R + 16n
  // R write bases, uniform in m: row (16m+li), column 16w+4g.
  u16* rqw = &sRq[(size_t)li * ST_R + 16 * w + 4 * g];   // + m*16*ST_R
  u16* rkw = &sRk[(size_t)li * ST_R + 16 * w + 4 * g];   // + m*16*ST_R
  // E fragment bases, uniform in m: row (16m+li).
  const u16* e0base = &sE[SWZ(li, 8 * g)];               // + m*1024
  const u16* e1base = &sE[SWZ(li, 32 + 8 * g)];          // + m*1024

  const int sidx2 = w * 2 * 64 + lane;
  const int sidx4 = w * 4 * 64 + lane;

  // ---- prologue: stage K(0), E(0); drain ----
  {
    const int eb0 = 1984 + q0;
#pragma unroll
    for (int i = 0; i < 2; ++i) {
      const int idx = sidx2 + i * 64;
      const int row = idx >> 3, sch = (idx & 7) ^ (row & 7);
      async_copy16(&sK0[(w * 2 + i) * 512], K + qkbase + (size_t)row * HID + sch * 8);
    }
#pragma unroll
    for (int i = 0; i < 4; ++i) {
      const int idx = sidx4 + i * 64;
      const int row = idx >> 3, sch = (idx & 7) ^ (row & 7);
      const int er = min(max(eb0 + row, 0), 2 * MAXP - 2);
      async_copy16(&sE[(w * 4 + i) * 512], E + (size_t)er * HD + sch * 8);
    }
    vwait0();
  }

  for (int k0 = 0; k0 < SEQ; k0 += 64) {
    const int p = (k0 >> 6) & 1;
    u16* kcur = p ? sK1 : sK0;
    u16* knxt = p ? sK0 : sK1;

    __builtin_amdgcn_s_barrier();   // #1: K(t),E(t) visible; knxt/sV reusable
    // ---- issue V(t) first (oldest), then K(t+1) ----
#pragma unroll
    for (int i = 0; i < 2; ++i) {
      const int idx = sidx2 + i * 64;
      const int row = idx >> 3, sch = (idx & 7) ^ (row & 7);
      async_copy16(&sV[(w * 2 + i) * 512], Vt + vtbase + (size_t)row * SEQ + k0 + sch * 8);
    }
#pragma unroll
    for (int i = 0; i < 2; ++i) {
      const int idx = sidx2 + i * 64;
      const int row = idx >> 3, sch = (idx & 7) ^ (row & 7);
      async_copy16(&knxt[(w * 2 + i) * 512], K + qkbase + (size_t)(k0 + 64 + row) * HID + sch * 8);
    }

    // ---- S = Q'.K^T (kB read once; kB[w] reused in R phase via template) ----
    bf16x8 kB[4][2];
#pragma unroll
    for (int n = 0; n < 4; ++n)
#pragma unroll
      for (int c = 0; c < 2; ++c)
        kB[n][c] = *reinterpret_cast<const bf16x8*>(&kcur[SWZ(16 * n + li, 32 * c + 8 * g)]);
    f32x4 aqk[4];
#pragma unroll
    for (int n = 0; n < 4; ++n) {
      aqk[n] = (f32x4)0.0f;
#pragma unroll
      for (int c = 0; c < 2; ++c)
        aqk[n] = __builtin_amdgcn_mfma_f32_16x16x32_bf16(qA[c], kB[n][c], aqk[n], 0, 0, 0);
    }

    // ---- band-restricted R, compile-time W (wave-uniform branch) ----
    __builtin_amdgcn_s_setprio(1);
    if (w == 0)      r_phase<0>(qA, kB[0], e0base, e1base, rqw, rkw);
    else if (w == 1) r_phase<1>(qA, kB[1], e0base, e1base, rqw, rkw);
    else if (w == 2) r_phase<2>(qA, kB[2], e0base, e1base, rqw, rkw);
    else             r_phase<3>(qA, kB[3], e0base, e1base, rqw, rkw);
    __builtin_amdgcn_s_setprio(0);

    vwait2();                       // V(t) landed (oldest 2); K(t+1) stays in flight
    lwait0();                       // R-writes retired
    __builtin_amdgcn_s_barrier();   // #2: sRk/sRq + sV visible to all

    // ---- issue E(t+1) (all sE reads happened before #2) ----
    {
      const int ebn = 1920 + q0 - k0;  // eb(t+1)
#pragma unroll
      for (int i = 0; i < 4; ++i) {
        const int idx = sidx4 + i * 64;
        const int row = idx >> 3, sch = (idx & 7) ^ (row & 7);
        const int er = min(max(ebn + row, 0), 2 * MAXP - 2);
        async_copy16(&sE[(w * 4 + i) * 512], E + (size_t)er * HD + sch * 8);
      }
    }

    // ---- scores: gather + __expf + P write (into kcur, dead K tile) ----
#pragma unroll
    for (int n = 0; n < 4; ++n)
#pragma unroll
      for (int r = 0; r < 4; ++r) {
        const float relq = bf2f(gqp[(48 + r - 16 * n) * ST_R + r]);
        const float relk = bf2f(gkp[(48 + r - 16 * n) * ST_R + 16 * n]);
        const float pr = __expf(fmaf(relk, 0.125f, aqk[n][r] + relq));
        kcur[SWZ(16 * w + 4 * g + r, 16 * n + li)] = f2bf_hw(pr);
      }

    // ---- O += P.V ; accX += P.1 (row-sum on matrix pipe) ----
    bf16x8 pA[2];
#pragma unroll
    for (int c = 0; c < 2; ++c)
      pA[c] = *reinterpret_cast<const bf16x8*>(&kcur[SWZ(16 * w + li, 32 * c + 8 * g)]);
#pragma unroll
    for (int n = 0; n < 4; ++n)
#pragma unroll
      for (int c = 0; c < 2; ++c) {
        const bf16x8 vB = *reinterpret_cast<const bf16x8*>(&sV[SWZ(16 * n + li, 32 * c + 8 * g)]);
        accO[n] = __builtin_amdgcn_mfma_f32_16x16x32_bf16(pA[c], vB, accO[n], 0, 0, 0);
      }
#pragma unroll
    for (int c = 0; c < 2; ++c)
      accX = __builtin_amdgcn_mfma_f32_16x16x32_bf16(pA[c], ones, accX, 0, 0, 0);

    vwait0();                       // K(t+1) + E(t+1) landed
  }

  // ---- epilogue: normalize (accX holds row-sums in every lane), store ----
#pragma unroll
  for (int r = 0; r < 4; ++r) {
    const float inv = 1.0f / accX[r];
    const size_t row = (size_t)(b * SEQ + q0 + 16 * w + 4 * g + r) * HID + h * HD;
#pragma unroll
    for (int n = 0; n < 4; ++n) out[row + 16 * n + li] = accO[n][r] * inv;
  }
}

extern "C" void kernel_launch(void* const* d_in, const int* in_sizes, int n_in,
                              void* d_out, int out_size, void* d_ws, size_t ws_size,
                              hipStream_t stream) {
  const float* hs = (const float*)d_in[0];
  const float* Wq = (const float*)d_in[1];
  const float* bq = (const float*)d_in[2];
  const float* Wk = (const float*)d_in[3];
  const float* bk = (const float*)d_in[4];
  const float* Wv = (const float*)d_in[5];
  const float* bv = (const float*)d_in[6];
  const float* de = (const float*)d_in[7];
  float* out = (float*)d_out;

  // Sizes: hs = 4,194,304 floats; W* = 1,048,576; de = 262,080.
  u16* Xb  = (u16*)d_ws;                 // 4,194,304 u16
  u16* Wqb = Xb + (size_t)4194304;       // 1,048,576 each
  u16* Wkb = Wqb + (size_t)1048576;
  u16* Wvb = Wkb + (size_t)1048576;
  u16* Qb  = Wvb + (size_t)1048576;      // 4,194,304 each
  u16* Kb  = Qb + (size_t)4194304;
  u16* Vb  = Kb + (size_t)4194304;
  u16* Eb  = Vb + (size_t)4194304;       // 262,080
  u16* Vtb = Xb;                         // alias: Xb dead after proj_mfma

  dim3 blk(256);
  hipLaunchKernelGGL(cvt_multi, dim3(1024, 5), blk, 0, stream,
                     hs, Wq, Wk, Wv, de, Xb, Wqb, Wkb, Wvb, Eb);
  hipLaunchKernelGGL(proj_mfma, dim3(24, 32), blk, 0, stream,
                     Xb, Wqb, Wkb, Wvb, bq, bk, bv, Qb, Kb, Vb);
  hipLaunchKernelGGL(transpose_v, dim3(SEQ / 64, NH, 2), blk, 0, stream, Vb, Vtb);
  hipLaunchKernelGGL(attn_mfma13, dim3(SEQ / 64, NH, 2), blk, 0, stream, Qb, Kb, Vtb, Eb, out);
}

// Round 19
// 221.076 us; speedup vs baseline: 11.8521x; 1.0314x over previous
//
#include <hip/hip_runtime.h>
#include <hip/hip_bf16.h>

#define NH 16
#define HD 64
#define SEQ 2048
#define HID 1024
#define MAXP 2048
#define ST_R 76   // u16 stride of transposed R tiles; 152B rows: b64-aligned,
                  // and 6*li mod 32 covers all 16 even banks once -> 2-way reads

typedef float f32x4 __attribute__((ext_vector_type(4)));
typedef short bf16x8 __attribute__((ext_vector_type(8)));
typedef unsigned short u16;
typedef unsigned short u16x8 __attribute__((ext_vector_type(8)));

// Scalar HW convert; compiler fuses adjacent pairs into v_cvt_pk_bf16_f32 (m240).
__device__ __forceinline__ u16 f2bf_hw(float x) {
  union { __hip_bfloat16 h; u16 u; } v;
  v.h = __float2bfloat16(x);
  return v.u;
}
__device__ __forceinline__ unsigned pk2(float a, float b) {
  return (unsigned)f2bf_hw(a) | ((unsigned)f2bf_hw(b) << 16);
}
__device__ __forceinline__ float bf2f(u16 h) {
  union { unsigned u; float f; } v; v.u = ((unsigned)h) << 16;
  return v.f;
}

// XOR-swizzle for bf16 tiles with 64-elem (128B) row stride.
#define SWZ(r, c) ((r) * 64 + ((((c) >> 3) ^ ((r) & 7)) << 3) + ((c) & 7))

// async global->LDS 16B: LDS dest = wave-uniform base + lane*16; global src per-lane.
__device__ __forceinline__ void async_copy16(void* lds, const void* g) {
  __builtin_amdgcn_global_load_lds(
      (const __attribute__((address_space(1))) unsigned int*)g,
      (__attribute__((address_space(3))) unsigned int*)lds, 16, 0, 0);
}
__device__ __forceinline__ void vwait0() { asm volatile("s_waitcnt vmcnt(0)" ::: "memory"); }
__device__ __forceinline__ void vwait2() { asm volatile("s_waitcnt vmcnt(2)" ::: "memory"); }
__device__ __forceinline__ void lwait0() { asm volatile("s_waitcnt lgkmcnt(0)" ::: "memory"); }

// ---------------- fused fp32 -> bf16 bulk convert (5 regions, 1 launch) ----------------
__global__ __launch_bounds__(256) void cvt_multi(
    const float* __restrict__ s0, const float* __restrict__ s1,
    const float* __restrict__ s2, const float* __restrict__ s3,
    const float* __restrict__ s4,
    u16* __restrict__ d0, u16* __restrict__ d1, u16* __restrict__ d2,
    u16* __restrict__ d3, u16* __restrict__ d4) {
  const float* s; u16* d; int n4;
  switch (blockIdx.y) {
    case 0: s = s0; d = d0; n4 = 1048576; break;   // hidden_states
    case 1: s = s1; d = d1; n4 = 262144; break;    // Wq
    case 2: s = s2; d = d2; n4 = 262144; break;    // Wk
    case 3: s = s3; d = d3; n4 = 262144; break;    // Wv
    default: s = s4; d = d4; n4 = 65520; break;    // dist_emb
  }
  int i = blockIdx.x * 256 + threadIdx.x;
  const int stride = gridDim.x * 256;
  for (; i < n4; i += stride) {
    const float4 v = reinterpret_cast<const float4*>(s)[i];
    uint2 o;
    o.x = pk2(v.x, v.y);
    o.y = pk2(v.z, v.w);
    reinterpret_cast<uint2*>(d)[i] = o;
  }
}

// ---------------- Fused Q/K/V projection: O = bf16((X @ W^T + b) * scale) ----
// Q (wsel==0) pre-scaled by 0.125 (exact in bf16) to fold 1/sqrt(64).
__global__ __launch_bounds__(256) void proj_mfma(
    const u16* __restrict__ Xb, const u16* __restrict__ W0,
    const u16* __restrict__ W1, const u16* __restrict__ W2,
    const float* __restrict__ b0, const float* __restrict__ b1,
    const float* __restrict__ b2,
    u16* __restrict__ O0, u16* __restrict__ O1, u16* __restrict__ O2) {
  __shared__ u16 sA[128 * 64];
  __shared__ u16 sB[128 * 64];
  const int t = threadIdx.x, lane = t & 63, w = t >> 6;
  const int g = lane >> 4, li = lane & 15;
  const int wsel = blockIdx.x >> 3;
  const int n0 = (blockIdx.x & 7) * 128, m0 = blockIdx.y * 128;
  const u16* Wb = wsel == 0 ? W0 : (wsel == 1 ? W1 : W2);
  const float* bias = wsel == 0 ? b0 : (wsel == 1 ? b1 : b2);
  u16* Ob = wsel == 0 ? O0 : (wsel == 1 ? O1 : O2);
  const float oscale = wsel == 0 ? 0.125f : 1.0f;
  const int wr = w >> 1, wc = w & 1;

  f32x4 acc[4][4];
#pragma unroll
  for (int i = 0; i < 4; ++i)
#pragma unroll
    for (int j = 0; j < 4; ++j) acc[i][j] = (f32x4)0.0f;

  for (int k0 = 0; k0 < HID; k0 += 64) {
    __syncthreads();
#pragma unroll
    for (int i = 0; i < 4; ++i) {
      const int idx = (w * 4 + i) * 64 + lane;
      const int row = idx >> 3, sch = (idx & 7) ^ (row & 7);
      async_copy16(&sA[(w * 4 + i) * 512], Xb + (size_t)(m0 + row) * HID + k0 + sch * 8);
      async_copy16(&sB[(w * 4 + i) * 512], Wb + (size_t)(n0 + row) * HID + k0 + sch * 8);
    }
    __syncthreads();
    bf16x8 af[4][2], bfr[4][2];
#pragma unroll
    for (int i = 0; i < 4; ++i)
#pragma unroll
      for (int c = 0; c < 2; ++c)
        af[i][c] = *reinterpret_cast<const bf16x8*>(&sA[SWZ(wr * 64 + 16 * i + li, 32 * c + 8 * g)]);
#pragma unroll
    for (int j = 0; j < 4; ++j)
#pragma unroll
      for (int c = 0; c < 2; ++c)
        bfr[j][c] = *reinterpret_cast<const bf16x8*>(&sB[SWZ(wc * 64 + 16 * j + li, 32 * c + 8 * g)]);
#pragma unroll
    for (int i = 0; i < 4; ++i)
#pragma unroll
      for (int j = 0; j < 4; ++j)
#pragma unroll
        for (int c = 0; c < 2; ++c)
          acc[i][j] = __builtin_amdgcn_mfma_f32_16x16x32_bf16(af[i][c], bfr[j][c], acc[i][j], 0, 0, 0);
  }

#pragma unroll
  for (int j = 0; j < 4; ++j) {
    const float bj = bias[n0 + wc * 64 + 16 * j + li];
#pragma unroll
    for (int i = 0; i < 4; ++i)
#pragma unroll
      for (int r = 0; r < 4; ++r)
        Ob[(size_t)(m0 + wr * 64 + 16 * i + 4 * g + r) * HID + n0 + wc * 64 + 16 * j + li] =
            f2bf_hw((acc[i][j][r] + bj) * oscale);
  }
}

// ---------------- V transpose: Vt[b][h][d][s] <- V[b][s][h*64+d] ----------------
__global__ __launch_bounds__(256) void transpose_v(
    const u16* __restrict__ Vin, u16* __restrict__ Vt) {
  __shared__ u16 tile[64 * 65];
  const int t = threadIdx.x;
  const int s0 = blockIdx.x * 64, h = blockIdx.y, b = blockIdx.z;
  const int r = t >> 2, c0 = (t & 3) * 16;
  const u16* gp = Vin + (size_t)(b * SEQ + s0 + r) * HID + h * HD + c0;
  const u16x8 a0 = *reinterpret_cast<const u16x8*>(gp);
  const u16x8 a1 = *reinterpret_cast<const u16x8*>(gp + 8);
#pragma unroll
  for (int i = 0; i < 8; ++i) { tile[r * 65 + c0 + i] = a0[i]; tile[r * 65 + c0 + 8 + i] = a1[i]; }
  __syncthreads();
  const int d = t >> 2, sc = (t & 3) * 16;
  u16x8 o0, o1;
#pragma unroll
  for (int i = 0; i < 8; ++i) {
    o0[i] = tile[(sc + i) * 65 + d];
    o1[i] = tile[(sc + 8 + i) * 65 + d];
  }
  u16* op = Vt + ((size_t)(b * NH + h) * HD + d) * SEQ + s0 + sc;
  *reinterpret_cast<u16x8*>(op) = o0;
  *reinterpret_cast<u16x8*>(op + 8) = o1;
}

// ---------------- Fused MFMA attention (R15 final): band-restricted R phase,
// counted mid-iter wait, accX ones-MFMA denominator, ST_R=76.
// Best-measured variant: 183.8 us attn. R16-R18 LDS-dedupe variants were
// neutral-to-worse (dependency-chain/barrier-bound, not LDS-op-bound).
__global__ __launch_bounds__(256, 2) void attn_mfma11(
    const u16* __restrict__ Q, const u16* __restrict__ K,
    const u16* __restrict__ Vt, const u16* __restrict__ E,
    float* __restrict__ out) {
  __shared__ u16 sK0[64 * 64];     // K buffers; current one becomes P after #2
  __shared__ u16 sK1[64 * 64];
  __shared__ u16 sV[64 * 64];
  __shared__ u16 sE[128 * 64];
  __shared__ u16 sRq[128 * ST_R];  // [j][qi] transposed
  __shared__ u16 sRk[128 * ST_R];  // [j][ki]

  const int t = threadIdx.x;
  const int lane = t & 63, w = t >> 6;
  const int g = lane >> 4, li = lane & 15;
  const int q0 = blockIdx.x * 64;
  const int h = blockIdx.y, b = blockIdx.z;
  const size_t qkbase = (size_t)b * SEQ * HID + (size_t)h * HD;
  const size_t vtbase = (size_t)(b * NH + h) * HD * SEQ;

  bf16x8 qA[2];
#pragma unroll
  for (int c = 0; c < 2; ++c)
    qA[c] = *reinterpret_cast<const bf16x8*>(
        Q + qkbase + (size_t)(q0 + 16 * w + li) * HID + 32 * c + 8 * g);

  bf16x8 ones;
#pragma unroll
  for (int i = 0; i < 8; ++i) ones[i] = (short)0x3F80;  // bf16 1.0

  f32x4 accO[4];
  f32x4 accX = (f32x4)0.0f;   // row-sum of P (denominator) via ones-MFMA
#pragma unroll
  for (int n = 0; n < 4; ++n) accO[n] = (f32x4)0.0f;

  // k0-invariant gather/write bases; j = 63+qi-ki, biased so unrolled offsets
  // are non-negative compile-time constants.
  const int jb48 = 15 + 16 * w + 4 * g - li;             // in [0, 75]
  const u16* gqp = &sRq[jb48 * ST_R + 16 * w + 4 * g];   // + (48+r-16n)*ST_R + r
  const u16* gkp = &sRk[jb48 * ST_R + li];               // + (48+r-16n)*ST_R + 16n
  // Band-restricted R write bases (k0-invariant): Rq groups m=w+mm, Rk m=(3-w)+mm.
  u16* rqw = &sRq[(16 * w + li) * ST_R + 16 * w + 4 * g];          // + mm*16*ST_R
  u16* rkw = &sRk[(16 * (3 - w) + li) * ST_R + 16 * w + 4 * g];    // + mm*16*ST_R
  // Matching E fragment bases (rows 16*(w+mm)+li and 16*(3-w+mm)+li).
  const u16* eqb[2];
  const u16* ekb[2];
#pragma unroll
  for (int c = 0; c < 2; ++c) {
    eqb[c] = &sE[SWZ(16 * w + li, 32 * c + 8 * g)];                // + mm*1024
    ekb[c] = &sE[SWZ(16 * (3 - w) + li, 32 * c + 8 * g)];          // + mm*1024
  }

  const int sidx2 = w * 2 * 64 + lane;
  const int sidx4 = w * 4 * 64 + lane;

  // ---- prologue: stage K(0), E(0); drain ----
  {
    const int eb0 = 1984 + q0;
#pragma unroll
    for (int i = 0; i < 2; ++i) {
      const int idx = sidx2 + i * 64;
      const int row = idx >> 3, sch = (idx & 7) ^ (row & 7);
      async_copy16(&sK0[(w * 2 + i) * 512], K + qkbase + (size_t)row * HID + sch * 8);
    }
#pragma unroll
    for (int i = 0; i < 4; ++i) {
      const int idx = sidx4 + i * 64;
      const int row = idx >> 3, sch = (idx & 7) ^ (row & 7);
      const int er = min(max(eb0 + row, 0), 2 * MAXP - 2);
      async_copy16(&sE[(w * 4 + i) * 512], E + (size_t)er * HD + sch * 8);
    }
    vwait0();
  }

  for (int k0 = 0; k0 < SEQ; k0 += 64) {
    const int p = (k0 >> 6) & 1;
    u16* kcur = p ? sK1 : sK0;
    u16* knxt = p ? sK0 : sK1;

    __builtin_amdgcn_s_barrier();   // #1: K(t),E(t) visible; knxt/sV reusable
    // ---- issue V(t) first (oldest), then K(t+1) — enables counted mid-wait ----
#pragma unroll
    for (int i = 0; i < 2; ++i) {
      const int idx = sidx2 + i * 64;
      const int row = idx >> 3, sch = (idx & 7) ^ (row & 7);
      async_copy16(&sV[(w * 2 + i) * 512], Vt + vtbase + (size_t)row * SEQ + k0 + sch * 8);
    }
#pragma unroll
    for (int i = 0; i < 2; ++i) {
      const int idx = sidx2 + i * 64;
      const int row = idx >> 3, sch = (idx & 7) ^ (row & 7);
      async_copy16(&knxt[(w * 2 + i) * 512], K + qkbase + (size_t)(k0 + 64 + row) * HID + sch * 8);
    }

    // ---- S = Q'.K^T ----
    bf16x8 kA[2];
#pragma unroll
    for (int c = 0; c < 2; ++c)
      kA[c] = *reinterpret_cast<const bf16x8*>(&kcur[SWZ(16 * w + li, 32 * c + 8 * g)]);
    f32x4 aqk[4];
#pragma unroll
    for (int n = 0; n < 4; ++n) {
      aqk[n] = (f32x4)0.0f;
#pragma unroll
      for (int c = 0; c < 2; ++c) {
        const bf16x8 kB = *reinterpret_cast<const bf16x8*>(&kcur[SWZ(16 * n + li, 32 * c + 8 * g)]);
        aqk[n] = __builtin_amdgcn_mfma_f32_16x16x32_bf16(qA[c], kB, aqk[n], 0, 0, 0);
      }
    }
    // ---- band-restricted R: Rq groups w..w+4, Rk groups 3-w..7-w ----
    __builtin_amdgcn_s_setprio(1);
#pragma unroll
    for (int mm = 0; mm < 5; ++mm) {
      bf16x8 eq[2], ek[2];
#pragma unroll
      for (int c = 0; c < 2; ++c) {
        eq[c] = *reinterpret_cast<const bf16x8*>(eqb[c] + mm * 1024);
        ek[c] = *reinterpret_cast<const bf16x8*>(ekb[c] + mm * 1024);
      }
      f32x4 aq = (f32x4)0.0f, ak = (f32x4)0.0f;
#pragma unroll
      for (int c = 0; c < 2; ++c) {
        aq = __builtin_amdgcn_mfma_f32_16x16x32_bf16(qA[c], eq[c], aq, 0, 0, 0);
        ak = __builtin_amdgcn_mfma_f32_16x16x32_bf16(kA[c], ek[c], ak, 0, 0, 0);
      }
      uint2 dq, dk;
      dq.x = pk2(aq[0], aq[1]); dq.y = pk2(aq[2], aq[3]);
      dk.x = pk2(ak[0], ak[1]); dk.y = pk2(ak[2], ak[3]);
      *reinterpret_cast<uint2*>(rqw + mm * 16 * ST_R) = dq;
      *reinterpret_cast<uint2*>(rkw + mm * 16 * ST_R) = dk;
    }
    __builtin_amdgcn_s_setprio(0);

    vwait2();                       // V(t) landed (oldest 2); K(t+1) stays in flight
    lwait0();                       // R-writes retired
    __builtin_amdgcn_s_barrier();   // #2: sRk/sRq + sV visible to all

    // ---- issue E(t+1) (all sE reads happened before #2) ----
    {
      const int ebn = 1920 + q0 - k0;  // eb(t+1)
#pragma unroll
      for (int i = 0; i < 4; ++i) {
        const int idx = sidx4 + i * 64;
        const int row = idx >> 3, sch = (idx & 7) ^ (row & 7);
        const int er = min(max(ebn + row, 0), 2 * MAXP - 2);
        async_copy16(&sE[(w * 4 + i) * 512], E + (size_t)er * HD + sch * 8);
      }
    }

    // ---- scores: gather + __expf + P write (into kcur, dead K tile) ----
#pragma unroll
    for (int n = 0; n < 4; ++n)
#pragma unroll
      for (int r = 0; r < 4; ++r) {
        const float relq = bf2f(gqp[(48 + r - 16 * n) * ST_R + r]);
        const float relk = bf2f(gkp[(48 + r - 16 * n) * ST_R + 16 * n]);
        const float pr = __expf(fmaf(relk, 0.125f, aqk[n][r] + relq));
        kcur[SWZ(16 * w + 4 * g + r, 16 * n + li)] = f2bf_hw(pr);
      }

    // ---- O += P.V ; accX += P.1 (row-sum on matrix pipe) ----
    bf16x8 pA[2];
#pragma unroll
    for (int c = 0; c < 2; ++c)
      pA[c] = *reinterpret_cast<const bf16x8*>(&kcur[SWZ(16 * w + li, 32 * c + 8 * g)]);
#pragma unroll
    for (int n = 0; n < 4; ++n)
#pragma unroll
      for (int c = 0; c < 2; ++c) {
        const bf16x8 vB = *reinterpret_cast<const bf16x8*>(&sV[SWZ(16 * n + li, 32 * c + 8 * g)]);
        accO[n] = __builtin_amdgcn_mfma_f32_16x16x32_bf16(pA[c], vB, accO[n], 0, 0, 0);
      }
#pragma unroll
    for (int c = 0; c < 2; ++c)
      accX = __builtin_amdgcn_mfma_f32_16x16x32_bf16(pA[c], ones, accX, 0, 0, 0);

    vwait0();                       // K(t+1) (full-iter flight) + E(t+1) landed
  }

  // ---- epilogue: normalize (accX holds row-sums in every lane), store ----
#pragma unroll
  for (int r = 0; r < 4; ++r) {
    const float inv = 1.0f / accX[r];
    const size_t row = (size_t)(b * SEQ + q0 + 16 * w + 4 * g + r) * HID + h * HD;
#pragma unroll
    for (int n = 0; n < 4; ++n) out[row + 16 * n + li] = accO[n][r] * inv;
  }
}

extern "C" void kernel_launch(void* const* d_in, const int* in_sizes, int n_in,
                              void* d_out, int out_size, void* d_ws, size_t ws_size,
                              hipStream_t stream) {
  const float* hs = (const float*)d_in[0];
  const float* Wq = (const float*)d_in[1];
  const float* bq = (const float*)d_in[2];
  const float* Wk = (const float*)d_in[3];
  const float* bk = (const float*)d_in[4];
  const float* Wv = (const float*)d_in[5];
  const float* bv = (const float*)d_in[6];
  const float* de = (const float*)d_in[7];
  float* out = (float*)d_out;

  // Sizes: hs = 4,194,304 floats; W* = 1,048,576; de = 262,080.
  u16* Xb  = (u16*)d_ws;                 // 4,194,304 u16
  u16* Wqb = Xb + (size_t)4194304;       // 1,048,576 each
  u16* Wkb = Wqb + (size_t)1048576;
  u16* Wvb = Wkb + (size_t)1048576;
  u16* Qb  = Wvb + (size_t)1048576;      // 4,194,304 each
  u16* Kb  = Qb + (size_t)4194304;
  u16* Vb  = Kb + (size_t)4194304;
  u16* Eb  = Vb + (size_t)4194304;       // 262,080
  u16* Vtb = Xb;                         // alias: Xb dead after proj_mfma

  dim3 blk(256);
  hipLaunchKernelGGL(cvt_multi, dim3(1024, 5), blk, 0, stream,
                     hs, Wq, Wk, Wv, de, Xb, Wqb, Wkb, Wvb, Eb);
  hipLaunchKernelGGL(proj_mfma, dim3(24, 32), blk, 0, stream,
                     Xb, Wqb, Wkb, Wvb, bq, bk, bv, Qb, Kb, Vb);
  hipLaunchKernelGGL(transpose_v, dim3(SEQ / 64, NH, 2), blk, 0, stream, Vb, Vtb);
  hipLaunchKernelGGL(attn_mfma11, dim3(SEQ / 64, NH, 2), blk, 0, stream, Qb, Kb, Vtb, Eb, out);
}

// Round 20
// 217.673 us; speedup vs baseline: 12.0374x; 1.0156x over previous
//
#include <hip/hip_runtime.h>
#include <hip/hip_bf16.h>

#define NH 16
#define HD 64
#define SEQ 2048
#define HID 1024
#define MAXP 2048
#define ST_R 76   // u16 stride of transposed R tiles; 152B rows: b64-aligned,
                  // and 6*li mod 32 covers all 16 even banks once -> 2-way reads

typedef float f32x4 __attribute__((ext_vector_type(4)));
typedef short bf16x8 __attribute__((ext_vector_type(8)));
typedef unsigned short u16;
typedef unsigned short u16x8 __attribute__((ext_vector_type(8)));

// Scalar HW convert; compiler fuses adjacent pairs into v_cvt_pk_bf16_f32 (m240).
__device__ __forceinline__ u16 f2bf_hw(float x) {
  union { __hip_bfloat16 h; u16 u; } v;
  v.h = __float2bfloat16(x);
  return v.u;
}
__device__ __forceinline__ unsigned pk2(float a, float b) {
  return (unsigned)f2bf_hw(a) | ((unsigned)f2bf_hw(b) << 16);
}
__device__ __forceinline__ float bf2f(u16 h) {
  union { unsigned u; float f; } v; v.u = ((unsigned)h) << 16;
  return v.f;
}

// XOR-swizzle for bf16 tiles with 64-elem (128B) row stride.
#define SWZ(r, c) ((r) * 64 + ((((c) >> 3) ^ ((r) & 7)) << 3) + ((c) & 7))

// async global->LDS 16B: LDS dest = wave-uniform base + lane*16; global src per-lane.
__device__ __forceinline__ void async_copy16(void* lds, const void* g) {
  __builtin_amdgcn_global_load_lds(
      (const __attribute__((address_space(1))) unsigned int*)g,
      (__attribute__((address_space(3))) unsigned int*)lds, 16, 0, 0);
}
__device__ __forceinline__ void vwait0() { asm volatile("s_waitcnt vmcnt(0)" ::: "memory"); }
__device__ __forceinline__ void vwait2() { asm volatile("s_waitcnt vmcnt(2)" ::: "memory"); }
__device__ __forceinline__ void lwait0() { asm volatile("s_waitcnt lgkmcnt(0)" ::: "memory"); }

// ---------------- fused fp32 -> bf16 bulk convert (5 regions, 1 launch) ----------------
__global__ __launch_bounds__(256) void cvt_multi(
    const float* __restrict__ s0, const float* __restrict__ s1,
    const float* __restrict__ s2, const float* __restrict__ s3,
    const float* __restrict__ s4,
    u16* __restrict__ d0, u16* __restrict__ d1, u16* __restrict__ d2,
    u16* __restrict__ d3, u16* __restrict__ d4) {
  const float* s; u16* d; int n4;
  switch (blockIdx.y) {
    case 0: s = s0; d = d0; n4 = 1048576; break;   // hidden_states
    case 1: s = s1; d = d1; n4 = 262144; break;    // Wq
    case 2: s = s2; d = d2; n4 = 262144; break;    // Wk
    case 3: s = s3; d = d3; n4 = 262144; break;    // Wv
    default: s = s4; d = d4; n4 = 65520; break;    // dist_emb
  }
  int i = blockIdx.x * 256 + threadIdx.x;
  const int stride = gridDim.x * 256;
  for (; i < n4; i += stride) {
    const float4 v = reinterpret_cast<const float4*>(s)[i];
    uint2 o;
    o.x = pk2(v.x, v.y);
    o.y = pk2(v.z, v.w);
    reinterpret_cast<uint2*>(d)[i] = o;
  }
}

// ---------------- Fused Q/K/V projection ----------------
// Q (wsel==0) pre-scaled by 0.125 (exact in bf16) to fold 1/sqrt(64).
// V (wsel==2) is written TRANSPOSED to Vt[b][h][d][s] via an LDS round-trip
// through the (dead after k-loop) 32KB staging buffer — eliminates the
// separate transpose_v kernel (8MB write + 8MB read + dispatch).
__global__ __launch_bounds__(256) void proj_mfma(
    const u16* __restrict__ Xb, const u16* __restrict__ W0,
    const u16* __restrict__ W1, const u16* __restrict__ W2,
    const float* __restrict__ b0, const float* __restrict__ b1,
    const float* __restrict__ b2,
    u16* __restrict__ O0, u16* __restrict__ O1, u16* __restrict__ Vt) {
  __shared__ u16 sAB[2 * 128 * 64];   // A-tile | B-tile; reused as 128x128 T
  u16* sA = sAB;
  u16* sB = sAB + 128 * 64;
  const int t = threadIdx.x, lane = t & 63, w = t >> 6;
  const int g = lane >> 4, li = lane & 15;
  const int wsel = blockIdx.x >> 3;
  const int n0 = (blockIdx.x & 7) * 128, m0 = blockIdx.y * 128;
  const u16* Wb = wsel == 0 ? W0 : (wsel == 1 ? W1 : W2);
  const int wr = w >> 1, wc = w & 1;

  f32x4 acc[4][4];
#pragma unroll
  for (int i = 0; i < 4; ++i)
#pragma unroll
    for (int j = 0; j < 4; ++j) acc[i][j] = (f32x4)0.0f;

  for (int k0 = 0; k0 < HID; k0 += 64) {
    __syncthreads();
#pragma unroll
    for (int i = 0; i < 4; ++i) {
      const int idx = (w * 4 + i) * 64 + lane;
      const int row = idx >> 3, sch = (idx & 7) ^ (row & 7);
      async_copy16(&sA[(w * 4 + i) * 512], Xb + (size_t)(m0 + row) * HID + k0 + sch * 8);
      async_copy16(&sB[(w * 4 + i) * 512], Wb + (size_t)(n0 + row) * HID + k0 + sch * 8);
    }
    __syncthreads();
    bf16x8 af[4][2], bfr[4][2];
#pragma unroll
    for (int i = 0; i < 4; ++i)
#pragma unroll
      for (int c = 0; c < 2; ++c)
        af[i][c] = *reinterpret_cast<const bf16x8*>(&sA[SWZ(wr * 64 + 16 * i + li, 32 * c + 8 * g)]);
#pragma unroll
    for (int j = 0; j < 4; ++j)
#pragma unroll
      for (int c = 0; c < 2; ++c)
        bfr[j][c] = *reinterpret_cast<const bf16x8*>(&sB[SWZ(wc * 64 + 16 * j + li, 32 * c + 8 * g)]);
#pragma unroll
    for (int i = 0; i < 4; ++i)
#pragma unroll
      for (int j = 0; j < 4; ++j)
#pragma unroll
        for (int c = 0; c < 2; ++c)
          acc[i][j] = __builtin_amdgcn_mfma_f32_16x16x32_bf16(af[i][c], bfr[j][c], acc[i][j], 0, 0, 0);
  }

  if (wsel < 2) {
    // ---- Q/K: standard row-major epilogue ----
    u16* Ob = wsel == 0 ? O0 : O1;
    const float* bias = wsel == 0 ? b0 : b1;
    const float oscale = wsel == 0 ? 0.125f : 1.0f;
#pragma unroll
    for (int j = 0; j < 4; ++j) {
      const float bj = bias[n0 + wc * 64 + 16 * j + li];
#pragma unroll
      for (int i = 0; i < 4; ++i)
#pragma unroll
        for (int r = 0; r < 4; ++r)
          Ob[(size_t)(m0 + wr * 64 + 16 * i + 4 * g + r) * HID + n0 + wc * 64 + 16 * j + li] =
              f2bf_hw((acc[i][j][r] + bj) * oscale);
    }
  } else {
    // ---- V: transposed epilogue through the dead staging LDS ----
    __syncthreads();   // all sA/sB k-loop reads complete
    u16 (*T)[128] = reinterpret_cast<u16 (*)[128]>(sAB);
#pragma unroll
    for (int j = 0; j < 4; ++j) {
      const float bj = b2[n0 + wc * 64 + 16 * j + li];
#pragma unroll
      for (int i = 0; i < 4; ++i)
#pragma unroll
        for (int r = 0; r < 4; ++r)
          T[wr * 64 + 16 * i + 4 * g + r][wc * 64 + 16 * j + li] =
              f2bf_hw(acc[i][j][r] + bj);
    }
    __syncthreads();
    // thread t: (h,d) column colL = t>>1, s-chunk (t&1)*64; reads are
    // 4-lane same-dword broadcasts across 16 banks (conflict-free).
    const int colL = t >> 1;
    const int s0l = (t & 1) * 64;
    const int col = n0 + colL;
    const int hh = col >> 6, dd = col & 63;
    const int bb = m0 >> 11;                // SEQ = 2048
    const int sg = (m0 & 2047) + s0l;
    u16* dst = Vt + ((size_t)(bb * NH + hh) * HD + dd) * SEQ + sg;
#pragma unroll
    for (int c8 = 0; c8 < 8; ++c8) {
      u16x8 v;
#pragma unroll
      for (int i = 0; i < 8; ++i) v[i] = T[s0l + c8 * 8 + i][colL];
      *reinterpret_cast<u16x8*>(dst + c8 * 8) = v;
    }
  }
}

// ---------------- Fused MFMA attention (R15 final): band-restricted R phase,
// counted mid-iter wait, accX ones-MFMA denominator, ST_R=76.
__global__ __launch_bounds__(256, 2) void attn_mfma11(
    const u16* __restrict__ Q, const u16* __restrict__ K,
    const u16* __restrict__ Vt, const u16* __restrict__ E,
    float* __restrict__ out) {
  __shared__ u16 sK0[64 * 64];     // K buffers; current one becomes P after #2
  __shared__ u16 sK1[64 * 64];
  __shared__ u16 sV[64 * 64];
  __shared__ u16 sE[128 * 64];
  __shared__ u16 sRq[128 * ST_R];  // [j][qi] transposed
  __shared__ u16 sRk[128 * ST_R];  // [j][ki]

  const int t = threadIdx.x;
  const int lane = t & 63, w = t >> 6;
  const int g = lane >> 4, li = lane & 15;
  const int q0 = blockIdx.x * 64;
  const int h = blockIdx.y, b = blockIdx.z;
  const size_t qkbase = (size_t)b * SEQ * HID + (size_t)h * HD;
  const size_t vtbase = (size_t)(b * NH + h) * HD * SEQ;

  bf16x8 qA[2];
#pragma unroll
  for (int c = 0; c < 2; ++c)
    qA[c] = *reinterpret_cast<const bf16x8*>(
        Q + qkbase + (size_t)(q0 + 16 * w + li) * HID + 32 * c + 8 * g);

  bf16x8 ones;
#pragma unroll
  for (int i = 0; i < 8; ++i) ones[i] = (short)0x3F80;  // bf16 1.0

  f32x4 accO[4];
  f32x4 accX = (f32x4)0.0f;   // row-sum of P (denominator) via ones-MFMA
#pragma unroll
  for (int n = 0; n < 4; ++n) accO[n] = (f32x4)0.0f;

  // k0-invariant gather/write bases; j = 63+qi-ki, biased so unrolled offsets
  // are non-negative compile-time constants.
  const int jb48 = 15 + 16 * w + 4 * g - li;             // in [0, 75]
  const u16* gqp = &sRq[jb48 * ST_R + 16 * w + 4 * g];   // + (48+r-16n)*ST_R + r
  const u16* gkp = &sRk[jb48 * ST_R + li];               // + (48+r-16n)*ST_R + 16n
  // Band-restricted R write bases (k0-invariant): Rq groups m=w+mm, Rk m=(3-w)+mm.
  u16* rqw = &sRq[(16 * w + li) * ST_R + 16 * w + 4 * g];          // + mm*16*ST_R
  u16* rkw = &sRk[(16 * (3 - w) + li) * ST_R + 16 * w + 4 * g];    // + mm*16*ST_R
  // Matching E fragment bases (rows 16*(w+mm)+li and 16*(3-w+mm)+li).
  const u16* eqb[2];
  const u16* ekb[2];
#pragma unroll
  for (int c = 0; c < 2; ++c) {
    eqb[c] = &sE[SWZ(16 * w + li, 32 * c + 8 * g)];                // + mm*1024
    ekb[c] = &sE[SWZ(16 * (3 - w) + li, 32 * c + 8 * g)];          // + mm*1024
  }

  const int sidx2 = w * 2 * 64 + lane;
  const int sidx4 = w * 4 * 64 + lane;

  // ---- prologue: stage K(0), E(0); drain ----
  {
    const int eb0 = 1984 + q0;
#pragma unroll
    for (int i = 0; i < 2; ++i) {
      const int idx = sidx2 + i * 64;
      const int row = idx >> 3, sch = (idx & 7) ^ (row & 7);
      async_copy16(&sK0[(w * 2 + i) * 512], K + qkbase + (size_t)row * HID + sch * 8);
    }
#pragma unroll
    for (int i = 0; i < 4; ++i) {
      const int idx = sidx4 + i * 64;
      const int row = idx >> 3, sch = (idx & 7) ^ (row & 7);
      const int er = min(max(eb0 + row, 0), 2 * MAXP - 2);
      async_copy16(&sE[(w * 4 + i) * 512], E + (size_t)er * HD + sch * 8);
    }
    vwait0();
  }

  for (int k0 = 0; k0 < SEQ; k0 += 64) {
    const int p = (k0 >> 6) & 1;
    u16* kcur = p ? sK1 : sK0;
    u16* knxt = p ? sK0 : sK1;

    __builtin_amdgcn_s_barrier();   // #1: K(t),E(t) visible; knxt/sV reusable
    // ---- issue V(t) first (oldest), then K(t+1) — enables counted mid-wait ----
#pragma unroll
    for (int i = 0; i < 2; ++i) {
      const int idx = sidx2 + i * 64;
      const int row = idx >> 3, sch = (idx & 7) ^ (row & 7);
      async_copy16(&sV[(w * 2 + i) * 512], Vt + vtbase + (size_t)row * SEQ + k0 + sch * 8);
    }
#pragma unroll
    for (int i = 0; i < 2; ++i) {
      const int idx = sidx2 + i * 64;
      const int row = idx >> 3, sch = (idx & 7) ^ (row & 7);
      async_copy16(&knxt[(w * 2 + i) * 512], K + qkbase + (size_t)(k0 + 64 + row) * HID + sch * 8);
    }

    // ---- S = Q'.K^T ----
    bf16x8 kA[2];
#pragma unroll
    for (int c = 0; c < 2; ++c)
      kA[c] = *reinterpret_cast<const bf16x8*>(&kcur[SWZ(16 * w + li, 32 * c + 8 * g)]);
    f32x4 aqk[4];
#pragma unroll
    for (int n = 0; n < 4; ++n) {
      aqk[n] = (f32x4)0.0f;
#pragma unroll
      for (int c = 0; c < 2; ++c) {
        const bf16x8 kB = *reinterpret_cast<const bf16x8*>(&kcur[SWZ(16 * n + li, 32 * c + 8 * g)]);
        aqk[n] = __builtin_amdgcn_mfma_f32_16x16x32_bf16(qA[c], kB, aqk[n], 0, 0, 0);
      }
    }
    // ---- band-restricted R: Rq groups w..w+4, Rk groups 3-w..7-w ----
    __builtin_amdgcn_s_setprio(1);
#pragma unroll
    for (int mm = 0; mm < 5; ++mm) {
      bf16x8 eq[2], ek[2];
#pragma unroll
      for (int c = 0; c < 2; ++c) {
        eq[c] = *reinterpret_cast<const bf16x8*>(eqb[c] + mm * 1024);
        ek[c] = *reinterpret_cast<const bf16x8*>(ekb[c] + mm * 1024);
      }
      f32x4 aq = (f32x4)0.0f, ak = (f32x4)0.0f;
#pragma unroll
      for (int c = 0; c < 2; ++c) {
        aq = __builtin_amdgcn_mfma_f32_16x16x32_bf16(qA[c], eq[c], aq, 0, 0, 0);
        ak = __builtin_amdgcn_mfma_f32_16x16x32_bf16(kA[c], ek[c], ak, 0, 0, 0);
      }
      uint2 dq, dk;
      dq.x = pk2(aq[0], aq[1]); dq.y = pk2(aq[2], aq[3]);
      dk.x = pk2(ak[0], ak[1]); dk.y = pk2(ak[2], ak[3]);
      *reinterpret_cast<uint2*>(rqw + mm * 16 * ST_R) = dq;
      *reinterpret_cast<uint2*>(rkw + mm * 16 * ST_R) = dk;
    }
    __builtin_amdgcn_s_setprio(0);

    vwait2();                       // V(t) landed (oldest 2); K(t+1) stays in flight
    lwait0();                       // R-writes retired
    __builtin_amdgcn_s_barrier();   // #2: sRk/sRq + sV visible to all

    // ---- issue E(t+1) (all sE reads happened before #2) ----
    {
      const int ebn = 1920 + q0 - k0;  // eb(t+1)
#pragma unroll
      for (int i = 0; i < 4; ++i) {
        const int idx = sidx4 + i * 64;
        const int row = idx >> 3, sch = (idx & 7) ^ (row & 7);
        const int er = min(max(ebn + row, 0), 2 * MAXP - 2);
        async_copy16(&sE[(w * 4 + i) * 512], E + (size_t)er * HD + sch * 8);
      }
    }

    // ---- scores: gather + __expf + P write (into kcur, dead K tile) ----
#pragma unroll
    for (int n = 0; n < 4; ++n)
#pragma unroll
      for (int r = 0; r < 4; ++r) {
        const float relq = bf2f(gqp[(48 + r - 16 * n) * ST_R + r]);
        const float relk = bf2f(gkp[(48 + r - 16 * n) * ST_R + 16 * n]);
        const float pr = __expf(fmaf(relk, 0.125f, aqk[n][r] + relq));
        kcur[SWZ(16 * w + 4 * g + r, 16 * n + li)] = f2bf_hw(pr);
      }

    // ---- O += P.V ; accX += P.1 (row-sum on matrix pipe) ----
    bf16x8 pA[2];
#pragma unroll
    for (int c = 0; c < 2; ++c)
      pA[c] = *reinterpret_cast<const bf16x8*>(&kcur[SWZ(16 * w + li, 32 * c + 8 * g)]);
#pragma unroll
    for (int n = 0; n < 4; ++n)
#pragma unroll
      for (int c = 0; c < 2; ++c) {
        const bf16x8 vB = *reinterpret_cast<const bf16x8*>(&sV[SWZ(16 * n + li, 32 * c + 8 * g)]);
        accO[n] = __builtin_amdgcn_mfma_f32_16x16x32_bf16(pA[c], vB, accO[n], 0, 0, 0);
      }
#pragma unroll
    for (int c = 0; c < 2; ++c)
      accX = __builtin_amdgcn_mfma_f32_16x16x32_bf16(pA[c], ones, accX, 0, 0, 0);

    vwait0();                       // K(t+1) (full-iter flight) + E(t+1) landed
  }

  // ---- epilogue: normalize (accX holds row-sums in every lane), store ----
#pragma unroll
  for (int r = 0; r < 4; ++r) {
    const float inv = 1.0f / accX[r];
    const size_t row = (size_t)(b * SEQ + q0 + 16 * w + 4 * g + r) * HID + h * HD;
#pragma unroll
    for (int n = 0; n < 4; ++n) out[row + 16 * n + li] = accO[n][r] * inv;
  }
}

extern "C" void kernel_launch(void* const* d_in, const int* in_sizes, int n_in,
                              void* d_out, int out_size, void* d_ws, size_t ws_size,
                              hipStream_t stream) {
  const float* hs = (const float*)d_in[0];
  const float* Wq = (const float*)d_in[1];
  const float* bq = (const float*)d_in[2];
  const float* Wk = (const float*)d_in[3];
  const float* bk = (const float*)d_in[4];
  const float* Wv = (const float*)d_in[5];
  const float* bv = (const float*)d_in[6];
  const float* de = (const float*)d_in[7];
  float* out = (float*)d_out;

  // Sizes: hs = 4,194,304 floats; W* = 1,048,576; de = 262,080.
  u16* Xb  = (u16*)d_ws;                 // 4,194,304 u16
  u16* Wqb = Xb + (size_t)4194304;       // 1,048,576 each
  u16* Wkb = Wqb + (size_t)1048576;
  u16* Wvb = Wkb + (size_t)1048576;
  u16* Qb  = Wvb + (size_t)1048576;      // 4,194,304 each
  u16* Kb  = Qb + (size_t)4194304;
  u16* Vtb = Kb + (size_t)4194304;       // V written TRANSPOSED by proj_mfma
  u16* Eb  = Vtb + (size_t)4194304;      // 262,080

  dim3 blk(256);
  hipLaunchKernelGGL(cvt_multi, dim3(1024, 5), blk, 0, stream,
                     hs, Wq, Wk, Wv, de, Xb, Wqb, Wkb, Wvb, Eb);
  hipLaunchKernelGGL(proj_mfma, dim3(24, 32), blk, 0, stream,
                     Xb, Wqb, Wkb, Wvb, bq, bk, bv, Qb, Kb, Vtb);
  hipLaunchKernelGGL(attn_mfma11, dim3(SEQ / 64, NH, 2), blk, 0, stream, Qb, Kb, Vtb, Eb, out);
}